// Round 5
// baseline (254.992 us; speedup 1.0000x reference)
//
#include <hip/hip_runtime.h>
#include <stdint.h>

// QuantizedPatternMatcher — R20: MEASUREMENT ROUND + fused finish.
//
// R19 post-mortem: manual half-pattern pipeline REGRESSED vs R18 single
// buffer (106.8 vs 97.8 headline) — compiler scheduling beats manual here.
// Reverted to R18's match shape.
//
// Standing mystery: match est ~40-47us vs ~11us VALU floor, and the MFMA
// formulation was also ~5x ITS floor. Both formulations share one untested
// assumption: the VALU issue model (2cyc/wave64-instr, 4 waves/SIMD pack).
// Three rounds of blind theories judged only by headline subtraction.
//
// R20:
//  (a) match_ctl: pure-VALU control. Identical loop structure, but the 12
//      pattern loads/iter are replaced by 48 opaque v_xor_b32 inline-asm
//      ops (DCE-proof), and the loop runs 96 iters so dur ~47us => ABOVE
//      the 42us fill cutoff => full rocprof counters guaranteed.
//      Pre-committed read: 45-55us & VALUBusy>=85 => VALU model right,
//      attack loads next. ~2x slower & VALUBusy~50 => issue model wrong,
//      return to MFMA formulation. FETCH huge => spill. Occ low => resid.
//  (b) fixup fused into match via done[rb] ticket: last pattern-tile block
//      per row-block writes out[] (keys read via atomicMin(x,~0) = L2-
//      coherent read). One fewer dispatch+gap; permanent.
// Headline will regress ~+47us THIS ROUND ONLY (diagnostic cost).
#define NROW 8192
#define NPAT 1024

typedef unsigned int u32;

__device__ __forceinline__ u32 bin7(float v, float e0, float e1, float e2,
                                    float e3, float e4, float e5, float e6) {
  return (u32)((v > e0) + (v > e1) + (v > e2) + (v > e3) + (v > e4) +
               (v > e5) + (v > e6));
}

__device__ __forceinline__ void acc3(u32 b, int k, u32& p0, u32& p1, u32& p2) {
  p0 |= (b & 1u) << k;
  p1 |= ((b >> 1) & 1u) << k;
  p2 |= ((b >> 2) & 1u) << k;
}

// ---------------------------------------------------------------------------
// prep: quantize + pack bitplanes; init keys (=0xFFFFFFFF) and done (=0).
//   xplanes [8192][16][3] u32, pplanes [1024][16][3] u32.
// ---------------------------------------------------------------------------
__global__ __launch_bounds__(256) void prep_pc(
    const float* __restrict__ x, const float* __restrict__ patterns,
    const float* __restrict__ edges, u32* __restrict__ xplanes,
    u32* __restrict__ pplanes, u32* __restrict__ keys,
    u32* __restrict__ done) {
  const int bid = blockIdx.x, tid = threadIdx.x;
  if (bid >= 576) {  // 32 blocks: init keys + done
    const int r = (bid - 576) * 256 + tid;
    keys[r] = 0xFFFFFFFFu;
    if (bid == 576 && tid < 32) done[tid] = 0u;
    return;
  }
  const float e0 = edges[0], e1 = edges[1], e2 = edges[2], e3 = edges[3],
              e4 = edges[4], e5 = edges[5], e6 = edges[6];
  const float4* s4;
  u32* dst;
  if (bid < 512) {  // x: 8192 rows * 16 chunks
    const int i = bid * 256 + tid;
    s4 = reinterpret_cast<const float4*>(x + (size_t)i * 32);
    dst = xplanes + (size_t)i * 3;
  } else {  // patterns: 1024 * 16
    const int j = (bid - 512) * 256 + tid;
    s4 = reinterpret_cast<const float4*>(patterns + (size_t)j * 32);
    dst = pplanes + (size_t)j * 3;
  }
  u32 p0 = 0, p1 = 0, p2 = 0;
#pragma unroll
  for (int q = 0; q < 8; ++q) {
    const float4 a = s4[q];
    acc3(bin7(a.x, e0, e1, e2, e3, e4, e5, e6), q * 4 + 0, p0, p1, p2);
    acc3(bin7(a.y, e0, e1, e2, e3, e4, e5, e6), q * 4 + 1, p0, p1, p2);
    acc3(bin7(a.z, e0, e1, e2, e3, e4, e5, e6), q * 4 + 2, p0, p1, p2);
    acc3(bin7(a.w, e0, e1, e2, e3, e4, e5, e6), q * 4 + 3, p0, p1, p2);
  }
  dst[0] = p0;
  dst[1] = p1;
  dst[2] = p2;
}

__device__ __forceinline__ void load_rp(u32 (&rp)[48],
                                        const u32* __restrict__ xplanes,
                                        int row) {
  const uint4* __restrict__ rs =
      reinterpret_cast<const uint4*>(xplanes + (size_t)row * 48);
#pragma unroll
  for (int j = 0; j < 12; ++j) {
    const uint4 v = rs[j];
    rp[j * 4 + 0] = v.x;
    rp[j * 4 + 1] = v.y;
    rp[j * 4 + 2] = v.z;
    rp[j * 4 + 3] = v.w;
  }
}

__device__ __forceinline__ u32 comp16(const u32 (&rp)[48],
                                      const u32 (&sp)[48]) {
  u32 mis = 0;
#pragma unroll
  for (int c = 0; c < 16; ++c) {
    const u32 d = (rp[c * 3 + 0] ^ sp[c * 3 + 0]) |
                  (rp[c * 3 + 1] ^ sp[c * 3 + 1]) |
                  (rp[c * 3 + 2] ^ sp[c * 3 + 2]);
    mis += (u32)__popc(d);
  }
  return mis;
}

// ---------------------------------------------------------------------------
// match (R18 shape): grid 1024 = 32 row-blocks (slow) x 32 pattern-tiles
// (fast). 256 thr = 4 waves, ~4 blocks/CU. Single sp[48] buffer, unroll 1.
// Fused finish: done[rb] ticket; last tile-block per row-block writes out.
// ---------------------------------------------------------------------------
__global__ __launch_bounds__(256) void match_pc(
    const u32* __restrict__ xplanes, const u32* __restrict__ pplanes,
    u32* __restrict__ keys, u32* __restrict__ done, float* __restrict__ out) {
  const int tid = threadIdx.x;
  const int rb = blockIdx.x >> 5;  // row block, 0..31 (slow)
  const int pc = blockIdx.x & 31;  // pattern tile, 0..31 (fast)
  const int row = rb * 256 + tid;

  u32 rp[48];
  load_rp(rp, xplanes, row);

  u32 best = 0xFFFFFFFFu;
  const u32 pb = (u32)(pc << 5);
  const u32* __restrict__ pp = pplanes + (size_t)pc * (32 * 48);
#pragma unroll 1
  for (int p = 0; p < 32; ++p) {
    u32 sp[48];
    const uint4* __restrict__ ps = reinterpret_cast<const uint4*>(pp + p * 48);
#pragma unroll
    for (int j = 0; j < 12; ++j) {
      const uint4 v = ps[j];
      sp[j * 4 + 0] = v.x;
      sp[j * 4 + 1] = v.y;
      sp[j * 4 + 2] = v.z;
      sp[j * 4 + 3] = v.w;
    }
    const u32 mis = comp16(rp, sp);
    const u32 key = (mis << 10) | (pb + (u32)p);
    best = key < best ? key : best;
  }
  atomicMin(&keys[row], best);
  __threadfence();

  __shared__ u32 lastflag;
  if (tid == 0) lastflag = (atomicAdd(&done[rb], 1u) == 31u) ? 1u : 0u;
  __syncthreads();
  if (lastflag) {
    __threadfence();
    const u32 k = atomicMin(&keys[row], 0xFFFFFFFFu);  // L2-coherent read
    out[row] = (float)(k & 1023u);
    out[NROW + row] = (float)(512u - (k >> 10)) * (1.0f / 512.0f);
  }
}

// ---------------------------------------------------------------------------
// match_ctl: pure-VALU control. Same loop structure; loads replaced by 48
// opaque v_xor_b32 (inline asm — compiler cannot fold rp^(rp^seed)); 96
// iters => ~47us if the 2cyc/instr VALU model holds. Results discarded
// into keys2 (poisoned ws, never read).
// ---------------------------------------------------------------------------
__global__ __launch_bounds__(256) void match_ctl(
    const u32* __restrict__ xplanes, u32* __restrict__ keys2) {
  const int tid = threadIdx.x;
  const int row = (int)(blockIdx.x >> 5) * 256 + tid;

  u32 rp[48];
  load_rp(rp, xplanes, row);

  u32 seedv = (u32)(blockIdx.x * 2654435761u) | 1u;
  u32 best = 0xFFFFFFFFu;
#pragma unroll 1
  for (int p = 0; p < 96; ++p) {
    u32 sp[48];
#pragma unroll
    for (int j = 0; j < 48; ++j) {
      u32 t;
      asm("v_xor_b32 %0, %1, %2" : "=v"(t) : "v"(rp[j]), "v"(seedv));
      sp[j] = t;
    }
    const u32 mis = comp16(rp, sp);
    seedv = seedv * 1664525u + 1013904223u;
    const u32 key = (mis << 10) | (u32)(p & 31);
    best = key < best ? key : best;
  }
  atomicMin(&keys2[row], best);
}

extern "C" void kernel_launch(void* const* d_in, const int* in_sizes, int n_in,
                              void* d_out, int out_size, void* d_ws,
                              size_t ws_size, hipStream_t stream) {
  const float* x = (const float*)d_in[0];         // [8192, 512] f32
  const float* patterns = (const float*)d_in[1];  // [1024, 512] f32
  const float* edges = (const float*)d_in[2];     // [7] f32
  float* out = (float*)d_out;                     // 16384 f32

  u32* xplanes = (u32*)d_ws;                       // 1.57 MB
  u32* pplanes = xplanes + (size_t)NROW * 48;      // 196 KB
  u32* keys = pplanes + (size_t)NPAT * 48;         // 32 KB
  u32* done = keys + NROW;                         // 128 B
  u32* keys2 = done + 32;                          // 32 KB (ctl scratch)

  prep_pc<<<608, 256, 0, stream>>>(x, patterns, edges, xplanes, pplanes, keys,
                                   done);
  match_pc<<<1024, 256, 0, stream>>>(xplanes, pplanes, keys, done, out);
  match_ctl<<<1024, 256, 0, stream>>>(xplanes, keys2);
}

// Round 6
// 125.934 us; speedup vs baseline: 2.0248x; 2.0248x over previous
//
#include <hip/hip_runtime.h>
#include <stdint.h>

// QuantizedPatternMatcher — R21: bitplane popcount; pattern loads forced onto
// the VECTOR pipe (vL1, in-order vmcnt) + half-pattern software pipeline.
//
// R20 measurements (the round's purpose):
//  - match_ctl (pure VALU): 99us @ VALUBusy 87% => VALU delivers ~1.8x fewer
//    instr/cyc than the 2cyc model; calibrated match VALU floor ~22-25us.
//    Bitplane formulation still beats MFMA's ~37us — keep it.
//  - match_pc: 99.5us == ctl despite 4.4x less VALU => ~80% load stalls.
//    SGPR=96/VGPR=56 proves the uniform pattern loads went SCALAR: SMEM
//    returns OUT OF ORDER => every use forces lgkmcnt(0), draining ALL
//    outstanding loads => no pipelining possible (also explains R19's
//    regression: its half-buffers drained each other). K$ is also shared
//    across CUs => contention.
//
// R21: opaque-zero VGPR (asm mov) added to the pattern address => the
// uniformity pass cannot select s_load => global_load_dwordx4 with v-offset.
// VMEM is IN ORDER => compiler emits counted s_waitcnt vmcnt(N) for the
// R19-style A/B half-pattern rotation => loads for the next half fly under
// the current half's ~100cyc of VALU. All lanes load the same 16B => one
// coalesced request/iter/wave, served by per-CU vL1 (3KB tile; co-resident
// blocks share it: pc = bid&63 and block spacing 256 = 0 mod 64).
// Live set rp48+A24+B24+addr+z ~ 110 < 128 => no spill, 4 waves/SIMD.
// Fused finish of R20 dropped (coincident with 2x anomaly); R18 epilogue +
// fixup kernel restored. done[] removed.
#define NROW 8192
#define NPAT 1024

typedef unsigned int u32;
typedef unsigned char u8;

__device__ __forceinline__ u32 bin7(float v, float e0, float e1, float e2,
                                    float e3, float e4, float e5, float e6) {
  return (u32)((v > e0) + (v > e1) + (v > e2) + (v > e3) + (v > e4) +
               (v > e5) + (v > e6));
}

__device__ __forceinline__ void acc3(u32 b, int k, u32& p0, u32& p1, u32& p2) {
  p0 |= (b & 1u) << k;
  p1 |= ((b >> 1) & 1u) << k;
  p2 |= ((b >> 2) & 1u) << k;
}

// ---------------------------------------------------------------------------
// prep: quantize + pack bitplanes; init keys (=0xFFFFFFFF).
//   xplanes [8192][16][3] u32   (48 dwords = 192 B per row; per 32-dim chunk
//   pplanes [1024][16][3] u32    the 3 planes are contiguous)
// ---------------------------------------------------------------------------
__global__ __launch_bounds__(256) void prep_pc(
    const float* __restrict__ x, const float* __restrict__ patterns,
    const float* __restrict__ edges, u32* __restrict__ xplanes,
    u32* __restrict__ pplanes, u32* __restrict__ keys) {
  const int bid = blockIdx.x, tid = threadIdx.x;
  if (bid >= 576) {  // 32 blocks: init keys
    const int r = (bid - 576) * 256 + tid;
    keys[r] = 0xFFFFFFFFu;
    return;
  }
  const float e0 = edges[0], e1 = edges[1], e2 = edges[2], e3 = edges[3],
              e4 = edges[4], e5 = edges[5], e6 = edges[6];
  const float4* s4;
  u32* dst;
  if (bid < 512) {  // x: 8192 rows * 16 chunks
    const int i = bid * 256 + tid;
    s4 = reinterpret_cast<const float4*>(x + (size_t)i * 32);
    dst = xplanes + (size_t)i * 3;
  } else {  // patterns: 1024 * 16
    const int j = (bid - 512) * 256 + tid;
    s4 = reinterpret_cast<const float4*>(patterns + (size_t)j * 32);
    dst = pplanes + (size_t)j * 3;
  }
  u32 p0 = 0, p1 = 0, p2 = 0;
#pragma unroll
  for (int q = 0; q < 8; ++q) {
    const float4 a = s4[q];
    acc3(bin7(a.x, e0, e1, e2, e3, e4, e5, e6), q * 4 + 0, p0, p1, p2);
    acc3(bin7(a.y, e0, e1, e2, e3, e4, e5, e6), q * 4 + 1, p0, p1, p2);
    acc3(bin7(a.z, e0, e1, e2, e3, e4, e5, e6), q * 4 + 2, p0, p1, p2);
    acc3(bin7(a.w, e0, e1, e2, e3, e4, e5, e6), q * 4 + 3, p0, p1, p2);
  }
  dst[0] = p0;
  dst[1] = p1;
  dst[2] = p2;
}

// Load 24 dwords (one half-pattern: 8 chunks x 3 planes) as 6 uint4 from a
// byte pointer that includes the opaque-zero VGPR offset (=> VMEM path).
__device__ __forceinline__ void loadhalf(u32 (&d)[24], const u8* __restrict__ s) {
#pragma unroll
  for (int j = 0; j < 6; ++j) {
    const uint4 v = *reinterpret_cast<const uint4*>(s + j * 16);
    d[j * 4 + 0] = v.x;
    d[j * 4 + 1] = v.y;
    d[j * 4 + 2] = v.z;
    d[j * 4 + 3] = v.w;
  }
}

// 8 chunks of XOR/OR/popc against rp chunks c0..c0+7. 48 int VALU.
__device__ __forceinline__ u32 comp8(const u32 (&rp)[48], const u32 (&b)[24],
                                     int c0) {
  u32 mis = 0;
#pragma unroll
  for (int c = 0; c < 8; ++c) {
    const u32 d = (rp[(c0 + c) * 3 + 0] ^ b[c * 3 + 0]) |
                  (rp[(c0 + c) * 3 + 1] ^ b[c * 3 + 1]) |
                  (rp[(c0 + c) * 3 + 2] ^ b[c * 3 + 2]);
    mis += (u32)__popc(d);
  }
  return mis;
}

// ---------------------------------------------------------------------------
// match: grid 2048 = 32 row-blocks (slow) x 64 pattern-tiles (fast; 16
// patterns = 3KB, vL1-resident; co-resident blocks share the tile since
// 256 % 64 == 0). 256 thr = 4 waves. rp[48] in VGPRs. A/B half-pattern
// rotation over VMEM loads -> counted vmcnt pipelining by the compiler.
// ---------------------------------------------------------------------------
__global__ __launch_bounds__(256) void match_pc(
    const u32* __restrict__ xplanes, const u32* __restrict__ pplanes,
    u32* __restrict__ keys) {
  const int tid = threadIdx.x;
  const int rb = blockIdx.x >> 6;  // row block, 0..31 (slow)
  const int pc = blockIdx.x & 63;  // pattern tile, 0..63 (fast)
  const int row = rb * 256 + tid;

  u32 rp[48];
  {
    const uint4* __restrict__ rs =
        reinterpret_cast<const uint4*>(xplanes + (size_t)row * 48);
#pragma unroll
    for (int j = 0; j < 12; ++j) {
      const uint4 v = rs[j];
      rp[j * 4 + 0] = v.x;
      rp[j * 4 + 1] = v.y;
      rp[j * 4 + 2] = v.z;
      rp[j * 4 + 3] = v.w;
    }
  }

  // Opaque zero in a VGPR: address becomes lane-dependent as far as the
  // uniformity analysis knows => vector loads (global_load_dwordx4),
  // in-order vmcnt => counted waits => real software pipelining.
  u32 z;
  asm("v_mov_b32 %0, 0" : "=v"(z));
  const u8* __restrict__ pz =
      reinterpret_cast<const u8*>(pplanes + (size_t)pc * (16 * 48)) + z;

  u32 A[24], B[24];
  loadhalf(A, pz);  // prologue: half0 of pattern 0

  u32 best = 0xFFFFFFFFu;
  const u32 pb = (u32)(pc << 4);
#pragma unroll 1
  for (int p = 0; p < 16; ++p) {
    loadhalf(B, pz + p * 192 + 96);   // issue half1(p)
    u32 mis = comp8(rp, A, 0);        // compute half0(p) — covers B
    loadhalf(A, pz + (p + 1) * 192);  // issue half0(p+1); p=15 over-reads
                                      // 96B into the next tile / keys[]
                                      // (valid ws, value unused)
    mis += comp8(rp, B, 8);           // compute half1(p) — covers A
    const u32 key = (mis << 10) | (pb + (u32)p);
    best = key < best ? key : best;
  }
  atomicMin(&keys[row], best);
}

__global__ __launch_bounds__(256) void fixup_pc(const u32* __restrict__ keys,
                                                float* __restrict__ out) {
  const int r = blockIdx.x * 256 + threadIdx.x;
  const u32 k = keys[r];
  out[r] = (float)(k & 1023u);
  out[NROW + r] = (float)(512u - (k >> 10)) * (1.0f / 512.0f);
}

extern "C" void kernel_launch(void* const* d_in, const int* in_sizes, int n_in,
                              void* d_out, int out_size, void* d_ws,
                              size_t ws_size, hipStream_t stream) {
  const float* x = (const float*)d_in[0];         // [8192, 512] f32
  const float* patterns = (const float*)d_in[1];  // [1024, 512] f32
  const float* edges = (const float*)d_in[2];     // [7] f32
  float* out = (float*)d_out;                     // 16384 f32

  u32* xplanes = (u32*)d_ws;                       // 1.57 MB
  u32* pplanes = xplanes + (size_t)NROW * 48;      // 196 KB
  u32* keys = pplanes + (size_t)NPAT * 48;         // 32 KB

  prep_pc<<<608, 256, 0, stream>>>(x, patterns, edges, xplanes, pplanes, keys);
  match_pc<<<2048, 256, 0, stream>>>(xplanes, pplanes, keys);
  fixup_pc<<<32, 256, 0, stream>>>(keys, out);
}